// Round 1
// baseline (670.765 us; speedup 1.0000x reference)
//
#include <hip/hip_runtime.h>

// IF (integrate-and-fire) forward, T=4 timesteps, B=8, FEAT=1024*3072, fp32.
//
// Layout: x / out are [T*B, 1024, 3072] flat; thresh2 / dtmem are [1024*3072].
// Recurrence over t is independent per (b, feature) element. One thread owns
// one float4 of features and walks all B batches x T timesteps so the learned
// params are fetched exactly once per feature (minimal HBM traffic: ~830 MB).
// Memory-bound: roofline ~132 us @ 6.3 TB/s.

constexpr int T_STEPS = 4;
constexpr int B_SZ    = 8;

__global__ __launch_bounds__(256) void if_fwd_kernel(
    const float4* __restrict__ x,
    const float4* __restrict__ thresh2,
    const float4* __restrict__ dtmem,
    float4* __restrict__ out,
    int n4)                       // feature elements / 4 = 786432
{
    const int f = blockIdx.x * blockDim.x + threadIdx.x;
    if (f >= n4) return;

    const float4 th = thresh2[f];
    const float4 dt = dtmem[f];

#pragma unroll
    for (int b = 0; b < B_SZ; ++b) {
        // initial membrane: dtmem * thre
        float mx = dt.x * th.x;
        float my = dt.y * th.y;
        float mz = dt.z * th.z;
        float mw = dt.w * th.w;

#pragma unroll
        for (int t = 0; t < T_STEPS; ++t) {
            const long long idx = (long long)(t * B_SZ + b) * n4 + f;
            const float4 xv = x[idx];
            mx += xv.x; my += xv.y; mz += xv.z; mw += xv.w;

            float4 s;
            s.x = (mx - th.x >= 0.0f) ? th.x : 0.0f;
            s.y = (my - th.y >= 0.0f) ? th.y : 0.0f;
            s.z = (mz - th.z >= 0.0f) ? th.z : 0.0f;
            s.w = (mw - th.w >= 0.0f) ? th.w : 0.0f;

            out[idx] = s;

            mx -= s.x; my -= s.y; mz -= s.z; mw -= s.w;
        }
    }
}

extern "C" void kernel_launch(void* const* d_in, const int* in_sizes, int n_in,
                              void* d_out, int out_size, void* d_ws, size_t ws_size,
                              hipStream_t stream) {
    const float* x       = (const float*)d_in[0];   // [T*B*1024*3072]
    const float* thresh2 = (const float*)d_in[1];   // [1024*3072]
    const float* dtmem   = (const float*)d_in[2];   // [1024*3072]
    float* out = (float*)d_out;

    const int n  = in_sizes[1];      // 1024*3072 = 3,145,728
    const int n4 = n / 4;            // 786,432 float4 threads

    const int block = 256;
    const int grid  = (n4 + block - 1) / block;    // 3072 blocks

    if_fwd_kernel<<<grid, block, 0, stream>>>(
        (const float4*)x, (const float4*)thresh2, (const float4*)dtmem,
        (float4*)out, n4);
}

// Round 3
// 641.558 us; speedup vs baseline: 1.0455x; 1.0455x over previous
//
#include <hip/hip_runtime.h>

// IF (integrate-and-fire) forward, T=4 timesteps, B=8, FEAT=1024*3072, fp32.
//
// Layout: x / out are [T*B, 1024, 3072] flat; thresh2 / dtmem are [1024*3072].
// The recurrence is ONLY over t (T=4); batch b is parallel. One thread per
// (b, float4-feature): 4 loads in flight, short dependency chain, low VGPR,
// 24576 blocks of TLP. Param re-reads (8x per line) are made cheap by
// dispatching the 8 b-blocks of an f-chunk adjacently (bid = f_chunk*8 + b)
// so 7/8 hit L2/L3, and by streaming x/out with nontemporal loads/stores so
// the 805 MB stream doesn't evict the 25 MB param set.
// Memory-bound: ~830 MB HBM -> roofline ~132 us @ 6.3 TB/s achievable.
//
// NOTE: __builtin_nontemporal_* requires a native clang vector type, not
// HIP_vector_type<float,4> — hence vf4 below.

typedef float vf4 __attribute__((ext_vector_type(4)));

constexpr int T_STEPS = 4;
constexpr int B_SZ    = 8;

__global__ __launch_bounds__(256) void if_fwd_kernel(
    const vf4* __restrict__ x,
    const vf4* __restrict__ thresh2,
    const vf4* __restrict__ dtmem,
    vf4* __restrict__ out,
    int n4)                       // feature elements / 4 = 786432
{
    const int bid    = blockIdx.x;
    const int b      = bid & (B_SZ - 1);          // batch index
    const int fchunk = bid >> 3;                  // feature chunk
    const int f      = fchunk * 256 + threadIdx.x;
    if (f >= n4) return;

    // params: reused across the 8 adjacent b-blocks -> L2/L3 hits
    const vf4 th = thresh2[f];
    const vf4 dt = dtmem[f];

    vf4 m = dt * th;   // initial membrane: dtmem * thre

#pragma unroll
    for (int t = 0; t < T_STEPS; ++t) {
        const long long idx = (long long)(t * B_SZ + b) * n4 + f;
        const vf4 xv = __builtin_nontemporal_load(&x[idx]);
        m += xv;

        vf4 s;
        s.x = (m.x - th.x >= 0.0f) ? th.x : 0.0f;
        s.y = (m.y - th.y >= 0.0f) ? th.y : 0.0f;
        s.z = (m.z - th.z >= 0.0f) ? th.z : 0.0f;
        s.w = (m.w - th.w >= 0.0f) ? th.w : 0.0f;

        __builtin_nontemporal_store(s, &out[idx]);

        m -= s;
    }
}

extern "C" void kernel_launch(void* const* d_in, const int* in_sizes, int n_in,
                              void* d_out, int out_size, void* d_ws, size_t ws_size,
                              hipStream_t stream) {
    const float* x       = (const float*)d_in[0];   // [T*B*1024*3072]
    const float* thresh2 = (const float*)d_in[1];   // [1024*3072]
    const float* dtmem   = (const float*)d_in[2];   // [1024*3072]
    float* out = (float*)d_out;

    const int n  = in_sizes[1];      // 1024*3072 = 3,145,728
    const int n4 = n / 4;            // 786,432 float4 features

    const int block   = 256;
    const int fchunks = (n4 + block - 1) / block;   // 3072
    const int grid    = fchunks * B_SZ;             // 24,576 blocks

    if_fwd_kernel<<<grid, block, 0, stream>>>(
        (const vf4*)x, (const vf4*)thresh2, (const vf4*)dtmem,
        (vf4*)out, n4);
}

// Round 4
// 633.891 us; speedup vs baseline: 1.0582x; 1.0121x over previous
//
#include <hip/hip_runtime.h>

// IF (integrate-and-fire) forward, T=4 timesteps, B=8, FEAT=1024*3072, fp32.
//
// x / out: [T*B, 1024, 3072] flat fp32; thresh2 / dtmem: [1024*3072].
// Recurrence is only over t (T=4); b is parallel. One thread owns TWO float4
// feature chunks (f0, f0+256) for one batch b: 8 NT loads in flight to hide
// ~900-cycle HBM latency, short dependency chain, ~60 VGPRs.
//
// XCD-aware block swizzle: b = bid / fchunks, fchunk = bid % fchunks. Blocks
// sharing a param line have bids congruent mod 8 (fchunks = 1536 = 0 mod 8),
// so round-robin workgroup dispatch lands them on the SAME XCD -> thresh2 /
// dtmem re-reads hit the private L2 instead of bouncing to L3.
//
// x / out are touched exactly once -> nontemporal so the 805 MB stream does
// not evict the 25 MB param set from L2/L3.
// Memory-bound: ~830 MB HBM -> ~132 us floor @ 6.3 TB/s achievable.

typedef float vf4 __attribute__((ext_vector_type(4)));

constexpr int T_STEPS = 4;
constexpr int B_SZ    = 8;

__device__ __forceinline__ vf4 spike_of(vf4 m, vf4 th) {
    vf4 s;
    s.x = (m.x - th.x >= 0.0f) ? th.x : 0.0f;
    s.y = (m.y - th.y >= 0.0f) ? th.y : 0.0f;
    s.z = (m.z - th.z >= 0.0f) ? th.z : 0.0f;
    s.w = (m.w - th.w >= 0.0f) ? th.w : 0.0f;
    return s;
}

__global__ __launch_bounds__(256) void if_fwd_kernel(
    const vf4* __restrict__ x,
    const vf4* __restrict__ thresh2,
    const vf4* __restrict__ dtmem,
    vf4* __restrict__ out,
    int n4,          // feature float4 count = 786432
    int fchunks)     // n4 / 512 = 1536
{
    const int bid    = blockIdx.x;
    const int b      = bid / fchunks;            // batch index 0..7
    const int fchunk = bid - b * fchunks;

    const int f0 = fchunk * 512 + threadIdx.x;   // first chunk
    const int f1 = f0 + 256;                     // second chunk
    if (f1 >= n4) return;

    // params: cached reads (L2-resident thanks to XCD swizzle + NT streams)
    const vf4 th0 = thresh2[f0];
    const vf4 dt0 = dtmem[f0];
    const vf4 th1 = thresh2[f1];
    const vf4 dt1 = dtmem[f1];

    vf4 m0 = dt0 * th0;   // initial membrane: dtmem * thre
    vf4 m1 = dt1 * th1;

    const long long base = (long long)b * n4;

#pragma unroll
    for (int t = 0; t < T_STEPS; ++t) {
        const long long row = (long long)(t * B_SZ) * n4 + base;
        const vf4 xv0 = __builtin_nontemporal_load(&x[row + f0]);
        const vf4 xv1 = __builtin_nontemporal_load(&x[row + f1]);

        m0 += xv0;
        m1 += xv1;

        const vf4 s0 = spike_of(m0, th0);
        const vf4 s1 = spike_of(m1, th1);

        __builtin_nontemporal_store(s0, &out[row + f0]);
        __builtin_nontemporal_store(s1, &out[row + f1]);

        m0 -= s0;
        m1 -= s1;
    }
}

extern "C" void kernel_launch(void* const* d_in, const int* in_sizes, int n_in,
                              void* d_out, int out_size, void* d_ws, size_t ws_size,
                              hipStream_t stream) {
    const float* x       = (const float*)d_in[0];   // [T*B*1024*3072]
    const float* thresh2 = (const float*)d_in[1];   // [1024*3072]
    const float* dtmem   = (const float*)d_in[2];   // [1024*3072]
    float* out = (float*)d_out;

    const int n  = in_sizes[1];      // 1024*3072 = 3,145,728
    const int n4 = n / 4;            // 786,432 float4 features

    const int block   = 256;
    const int fchunks = n4 / (2 * block);           // 1536 (exact)
    const int grid    = fchunks * B_SZ;             // 12,288 blocks

    if_fwd_kernel<<<grid, block, 0, stream>>>(
        (const vf4*)x, (const vf4*)thresh2, (const vf4*)dtmem,
        (vf4*)out, n4, fchunks);
}